// Round 16
// baseline (131.740 us; speedup 1.0000x reference)
//
#include <hip/hip_runtime.h>

#define NDIM 128
#define BIN_SHIFT 7
#define BIN_NODES 128          // 1 << BIN_SHIFT
#define MAX_BINS 1024          // supports up to 131072 nodes
#define TILE 4096              // edges per bin-role block
#define CAP_SHIFT 12
#define BIN_CAP 4096           // padded per-bin capacity (avg fill ~2046)
#define QTR_CAP 1536           // per-quarter LDS src capacity (avg ~512, +45 sigma)

typedef __attribute__((ext_vector_type(8))) short short8;
typedef __attribute__((ext_vector_type(4))) float f32x4;
typedef __attribute__((ext_vector_type(4))) unsigned int u32x4;

__device__ inline unsigned short f2bf_rne(float f) {
    unsigned int u = __float_as_uint(f);
    unsigned int r = u + 0x7fffu + ((u >> 16) & 1u);
    return (unsigned short)(r >> 16);
}
__device__ inline float bf2f(unsigned short s) {
    return __uint_as_float(((unsigned int)s) << 16);
}
__device__ inline float bf_lo(unsigned int u) { return __uint_as_float(u << 16); }
__device__ inline float bf_hi(unsigned int u) { return __uint_as_float(u & 0xffff0000u); }

// HW packed f32->bf16 (RNE): dst = {lo16=bf16(a), hi16=bf16(b)}
__device__ inline unsigned int cvt_pk_bf16(float a, float b) {
    unsigned int r;
    asm("v_cvt_pk_bf16_f32 %0, %1, %2" : "=v"(r) : "v"(a), "v"(b));
    return r;
}

// ---------------------------------------------------------------------------
// fused_gemm_bin: block-role split (data-independent roles co-resident).
//   blocks [0, gemmBlocks)          : h = x @ W (pure bf16 MFMA, grid-stride)
//   blocks [gemmBlocks, +ntile_e)   : bin-scatter tile of TILE edges into
//                                     128-node bins (packed dstLow<<24|src).
// Gemm role keeps B-fragments t=0..3 in registers; t=4..7 read from LDS.
// binCursor is RELATIVE (memset 0 before launch).
// ---------------------------------------------------------------------------
__global__ __launch_bounds__(256, 4) void fused_gemm_bin(const float* __restrict__ x,
                                                         const float* __restrict__ W,
                                                         unsigned short* __restrict__ h,
                                                         const int* __restrict__ src,
                                                         const int* __restrict__ dst,
                                                         int* __restrict__ binCursor,
                                                         unsigned int* __restrict__ binned,
                                                         int n_nodes, int ntiles,
                                                         int n_edges, int nb,
                                                         int gemmBlocks) {
    __shared__ __align__(16) char smem[38144];
    const int tid = threadIdx.x;

    if ((int)blockIdx.x < gemmBlocks) {
        // ------------------- GEMM role -------------------
        unsigned short* Wt = (unsigned short*)smem;  // [128][128] bf16, k-swizzled

        const float4* W4 = (const float4*)W;
#pragma unroll
        for (int i = 0; i < 16; ++i) {
            const int vid = i * 256 + tid;
            const int k = vid >> 5;
            const int c4 = (vid & 31) * 4;
            const float4 w = W4[vid];
            const float* wf = (const float*)&w;
#pragma unroll
            for (int j = 0; j < 4; ++j) {
                const int col = c4 + j;
                const int ksw = k ^ ((col & 7) << 3);
                Wt[col * NDIM + ksw] = f2bf_rne(wf[j]);
            }
        }
        __syncthreads();

        const int wave = tid >> 6;
        const int lane = tid & 63;
        const int lc = lane & 15;
        const int kq = (lane >> 4) * 8;

        // B-fragments for t=0..3 in registers (tile-invariant)
        short8 breg[4][4];  // [ks][t]
#pragma unroll
        for (int ks = 0; ks < 4; ++ks) {
#pragma unroll
            for (int t = 0; t < 4; ++t) {
                const int col = t * 16 + lc;
                const int ksw = (ks * 32 + kq) ^ ((col & 7) << 3);
                breg[ks][t] = *(const short8*)&Wt[col * NDIM + ksw];
            }
        }

        for (int tile = blockIdx.x; tile < ntiles; tile += gemmBlocks) {
            const int row0 = tile * 64 + wave * 16;

            int arow = row0 + lc;
            arow = (arow < n_nodes) ? arow : (n_nodes - 1);
            const float* xr = x + (size_t)arow * NDIM;

            f32x4 acc[8];
#pragma unroll
            for (int t = 0; t < 8; ++t) acc[t] = (f32x4){0.f, 0.f, 0.f, 0.f};

#pragma unroll
            for (int ks = 0; ks < 4; ++ks) {
                const int kbase = ks * 32 + kq;
                const float4 v0 = *(const float4*)(xr + kbase);
                const float4 v1 = *(const float4*)(xr + kbase + 4);

                u32x4 ap;
                ap.x = cvt_pk_bf16(v0.x, v0.y);
                ap.y = cvt_pk_bf16(v0.z, v0.w);
                ap.z = cvt_pk_bf16(v1.x, v1.y);
                ap.w = cvt_pk_bf16(v1.z, v1.w);
                const short8 ah = *(const short8*)&ap;

#pragma unroll
                for (int t = 0; t < 4; ++t) {
                    acc[t] = __builtin_amdgcn_mfma_f32_16x16x32_bf16(ah, breg[ks][t], acc[t], 0, 0, 0);
                }
#pragma unroll
                for (int t = 4; t < 8; ++t) {
                    const int col = t * 16 + lc;
                    const int ksw = kbase ^ ((col & 7) << 3);
                    const short8 bh = *(const short8*)&Wt[col * NDIM + ksw];
                    acc[t] = __builtin_amdgcn_mfma_f32_16x16x32_bf16(ah, bh, acc[t], 0, 0, 0);
                }
            }

            const int orow0 = row0 + (lane >> 4) * 4;
#pragma unroll
            for (int t = 0; t < 8; ++t) {
#pragma unroll
                for (int r = 0; r < 4; ++r) {
                    const int row = orow0 + r;
                    if (row < n_nodes) {
                        h[(size_t)row * NDIM + t * 16 + lc] = f2bf_rne(acc[t][r]);
                    }
                }
            }
        }
        return;
    }

    // ------------------- BIN role -------------------
    int* lhist  = (int*)smem;                                  //  4096 B
    int* lstart = lhist + MAX_BINS;                            //  4096 B
    int* lcur   = lstart + MAX_BINS;                           //  4096 B
    int* lsums  = lcur + MAX_BINS;                             //  1024 B
    unsigned int* lsorted = (unsigned int*)(lsums + 256);      // 16384 B
    unsigned short* lbin  = (unsigned short*)(lsorted + TILE); //  8192 B (sum 37888)

    const int bblk = (int)blockIdx.x - gemmBlocks;
    const int base = bblk * TILE;
    const int count = min(TILE, n_edges - base);

    for (int i = tid; i < MAX_BINS; i += 256) lhist[i] = 0;
    __syncthreads();

    int mybin[16];
    unsigned int mypacked[16];
#pragma unroll
    for (int j = 0; j < 16; ++j) {
        const int idx = tid + j * 256;  // coalesced
        if (idx < count) {
            const int d = __builtin_nontemporal_load(dst + base + idx);
            const int s = __builtin_nontemporal_load(src + base + idx);
            mybin[j] = d >> BIN_SHIFT;
            mypacked[j] = ((unsigned int)(d & (BIN_NODES - 1)) << 24) | (unsigned int)s;
            atomicAdd(&lhist[mybin[j]], 1);
        } else {
            mybin[j] = -1;
            mypacked[j] = 0;
        }
    }
    __syncthreads();

    // exclusive scan over MAX_BINS=1024 (4 elems/thread)
    const int a0 = lhist[4 * tid], a1 = lhist[4 * tid + 1];
    const int a2 = lhist[4 * tid + 2], a3 = lhist[4 * tid + 3];
    lsums[tid] = a0 + a1 + a2 + a3;
    __syncthreads();
    for (int off = 1; off < 256; off <<= 1) {
        const int tmp = (tid >= off) ? lsums[tid - off] : 0;
        __syncthreads();
        lsums[tid] += tmp;
        __syncthreads();
    }
    int ex = (tid > 0) ? lsums[tid - 1] : 0;
    lstart[4 * tid] = ex;
    lcur[4 * tid] = ex;
    ex += a0;
    lstart[4 * tid + 1] = ex;
    lcur[4 * tid + 1] = ex;
    ex += a1;
    lstart[4 * tid + 2] = ex;
    lcur[4 * tid + 2] = ex;
    ex += a2;
    lstart[4 * tid + 3] = ex;
    lcur[4 * tid + 3] = ex;
    __syncthreads();

    // LDS scatter into bin-sorted order + bin LUT
#pragma unroll
    for (int j = 0; j < 16; ++j) {
        if (mybin[j] >= 0) {
            const int pos = atomicAdd(&lcur[mybin[j]], 1);
            lsorted[pos] = mypacked[j];
            lbin[pos] = (unsigned short)mybin[j];
        }
    }
    __syncthreads();

    // reserve global runs per bin (lcur becomes RELATIVE base per bin)
    for (int i = tid; i < nb; i += 256) {
        const int c = lhist[i];
        lcur[i] = c ? atomicAdd(&binCursor[i], c) : 0;
    }
    __syncthreads();

    // sequential write-out; per-slot bin via LUT
    for (int p = tid; p < count; p += 256) {
        const int bn = lbin[p];
        const int rel = lcur[bn] + (p - lstart[bn]);
        if (rel < BIN_CAP) {  // overflow guard
            binned[((size_t)bn << CAP_SHIFT) + rel] = lsorted[p];
        }
    }
}

// ---------------------------------------------------------------------------
// gather_bin: FOUR blocks (256 thr each) per 128-node bin; each block owns a
// 32-node quarter. In-LDS CSR build (filtered hist -> scan -> scatter into
// lout), then each of 4 waves gathers 8 nodes: 16-deep h-row unroll, fused
// epilogue out[n] = x[n] + relu(sum h[src] + b). 3128 blocks, ~6.5 KB LDS
// -> 8 blocks/CU (thread-capped) = full occupancy.
// ---------------------------------------------------------------------------
__global__ __launch_bounds__(256) void gather_bin(const unsigned short* __restrict__ h,
                                                  const unsigned int* __restrict__ binned,
                                                  const int* __restrict__ binCursor,
                                                  const float* __restrict__ x,
                                                  const float* __restrict__ bias,
                                                  float* __restrict__ out,
                                                  int n_nodes) {
    __shared__ int lhist[32];
    __shared__ int lstart[32];
    __shared__ int lcur[32];
    __shared__ int lout[QTR_CAP];
    const int b = blockIdx.x >> 2;
    const int q = (int)blockIdx.x & 3;
    const int tid = threadIdx.x;
    const size_t gbase = (size_t)b << CAP_SHIFT;
    int count = min(binCursor[b], BIN_CAP);
    const int node0 = b * BIN_NODES + q * 32;
    if (node0 >= n_nodes) return;

    if (tid < 32) lhist[tid] = 0;
    __syncthreads();

    // pass 1: filtered histogram (this block's 32-node quarter)
    for (int p = tid; p < count; p += 256) {
        const int dl = (int)(binned[gbase + p] >> 24);
        if ((dl >> 5) == q) atomicAdd(&lhist[dl & 31], 1);
    }
    __syncthreads();

    // inclusive scan of lhist[32] (Hillis-Steele)
    if (tid < 32) lstart[tid] = lhist[tid];
    __syncthreads();
    for (int off = 1; off < 32; off <<= 1) {
        int v = 0;
        if (tid < 32 && tid >= off) v = lstart[tid - off];
        __syncthreads();
        if (tid < 32 && tid >= off) lstart[tid] += v;
        __syncthreads();
    }
    int ex = 0;
    if (tid < 32) ex = (tid > 0) ? lstart[tid - 1] : 0;
    __syncthreads();
    if (tid < 32) {
        lstart[tid] = ex;
        lcur[tid] = ex;
    }
    __syncthreads();

    // pass 2: filtered scatter of src into per-node groups (binned L2-hot)
    for (int p = tid; p < count; p += 256) {
        const unsigned int v = binned[gbase + p];
        const int dl = (int)(v >> 24);
        if ((dl >> 5) == q) {
            const int pos = atomicAdd(&lcur[dl & 31], 1);
            if (pos < QTR_CAP) lout[pos] = (int)(v & 0xFFFFFFu);
        }
    }
    __syncthreads();

    // gather: wave w handles local nodes w*8 .. w*8+7 serially
    const int wave = tid >> 6;
    const int lane = tid & 63;
    const int c = lane * 2;
    const float2 bv = *(const float2*)(bias + c);

#pragma unroll 1
    for (int i = 0; i < 8; ++i) {
        const int ln = wave * 8 + i;
        const int node = node0 + ln;
        if (node >= n_nodes) break;
        const int start = lstart[ln];
        int cnt = lhist[ln];
        if (start + cnt > QTR_CAP) cnt = QTR_CAP - start;  // never in practice

        float ax = 0.f, ay = 0.f;
        int j = 0;
        for (; j + 16 <= cnt; j += 16) {
            int s[16];
#pragma unroll
            for (int k = 0; k < 16; ++k) s[k] = lout[start + j + k];
            unsigned int v[16];
#pragma unroll
            for (int k = 0; k < 16; ++k) v[k] = *(const unsigned int*)(h + (size_t)s[k] * NDIM + c);
#pragma unroll
            for (int k = 0; k < 16; ++k) { ax += bf_lo(v[k]); ay += bf_hi(v[k]); }
        }
        for (; j + 8 <= cnt; j += 8) {
            int s[8];
#pragma unroll
            for (int k = 0; k < 8; ++k) s[k] = lout[start + j + k];
            unsigned int v[8];
#pragma unroll
            for (int k = 0; k < 8; ++k) v[k] = *(const unsigned int*)(h + (size_t)s[k] * NDIM + c);
#pragma unroll
            for (int k = 0; k < 8; ++k) { ax += bf_lo(v[k]); ay += bf_hi(v[k]); }
        }
        for (; j + 4 <= cnt; j += 4) {
            int s[4];
#pragma unroll
            for (int k = 0; k < 4; ++k) s[k] = lout[start + j + k];
            unsigned int v[4];
#pragma unroll
            for (int k = 0; k < 4; ++k) v[k] = *(const unsigned int*)(h + (size_t)s[k] * NDIM + c);
#pragma unroll
            for (int k = 0; k < 4; ++k) { ax += bf_lo(v[k]); ay += bf_hi(v[k]); }
        }
        for (; j < cnt; ++j) {
            const int s0 = lout[start + j];
            const unsigned int v0 = *(const unsigned int*)(h + (size_t)s0 * NDIM + c);
            ax += bf_lo(v0);
            ay += bf_hi(v0);
        }

        const float2 xv = *(const float2*)(x + (size_t)node * NDIM + c);
        float2 r;
        r.x = xv.x + fmaxf(ax + bv.x, 0.f);
        r.y = xv.y + fmaxf(ay + bv.y, 0.f);
        *(float2*)(out + (size_t)node * NDIM + c) = r;
    }
}

// ---------------------------------------------------------------------------
// Fallback GEMM (standalone) + atomic scatter, used only if ws too small.
// ---------------------------------------------------------------------------
__global__ __launch_bounds__(256) void gemm128_bf16(const float* __restrict__ x,
                                                    const float* __restrict__ W,
                                                    unsigned short* __restrict__ h,
                                                    int n_nodes, int ntiles) {
    __shared__ __align__(16) unsigned short Wt[NDIM * NDIM];
    const int tid = threadIdx.x;
    const float4* W4 = (const float4*)W;
#pragma unroll
    for (int i = 0; i < 16; ++i) {
        const int vid = i * 256 + tid;
        const int k = vid >> 5;
        const int c4 = (vid & 31) * 4;
        const float4 w = W4[vid];
        const float* wf = (const float*)&w;
#pragma unroll
        for (int j = 0; j < 4; ++j) {
            const int col = c4 + j;
            const int ksw = k ^ ((col & 7) << 3);
            Wt[col * NDIM + ksw] = f2bf_rne(wf[j]);
        }
    }
    __syncthreads();
    const int wave = tid >> 6;
    const int lane = tid & 63;
    const int lc = lane & 15;
    const int kq = (lane >> 4) * 8;
    for (int tile = blockIdx.x; tile < ntiles; tile += gridDim.x) {
        const int row0 = tile * 64 + wave * 16;
        int arow = row0 + lc;
        arow = (arow < n_nodes) ? arow : (n_nodes - 1);
        const float* xr = x + (size_t)arow * NDIM;
        f32x4 acc[8];
#pragma unroll
        for (int t = 0; t < 8; ++t) acc[t] = (f32x4){0.f, 0.f, 0.f, 0.f};
#pragma unroll
        for (int ks = 0; ks < 4; ++ks) {
            const int kbase = ks * 32 + kq;
            const float4 v0 = *(const float4*)(xr + kbase);
            const float4 v1 = *(const float4*)(xr + kbase + 4);
            u32x4 ap;
            ap.x = cvt_pk_bf16(v0.x, v0.y);
            ap.y = cvt_pk_bf16(v0.z, v0.w);
            ap.z = cvt_pk_bf16(v1.x, v1.y);
            ap.w = cvt_pk_bf16(v1.z, v1.w);
            const short8 ah = *(const short8*)&ap;
#pragma unroll
            for (int t = 0; t < 8; ++t) {
                const int col = t * 16 + lc;
                const int ksw = kbase ^ ((col & 7) << 3);
                const short8 bh = *(const short8*)&Wt[col * NDIM + ksw];
                acc[t] = __builtin_amdgcn_mfma_f32_16x16x32_bf16(ah, bh, acc[t], 0, 0, 0);
            }
        }
        const int orow0 = row0 + (lane >> 4) * 4;
#pragma unroll
        for (int t = 0; t < 8; ++t) {
#pragma unroll
            for (int r = 0; r < 4; ++r) {
                const int row = orow0 + r;
                if (row < n_nodes) {
                    h[(size_t)row * NDIM + t * 16 + lc] = f2bf_rne(acc[t][r]);
                }
            }
        }
    }
}

__global__ __launch_bounds__(256) void scatter_add_bf(const unsigned short* __restrict__ h,
                                                      const int* __restrict__ src,
                                                      const int* __restrict__ dst,
                                                      float* __restrict__ agg,
                                                      int n_edges) {
    const int gid = blockIdx.x * 256 + threadIdx.x;
    const int e = gid >> 6;
    if (e >= n_edges) return;
    const int c = (gid & 63) * 2;
    const int s = src[e];
    const int d = dst[e];
    const unsigned int v = *(const unsigned int*)(h + (size_t)s * NDIM + c);
    float* ap = agg + (size_t)d * NDIM + c;
    atomicAdd(ap + 0, bf_lo(v));
    atomicAdd(ap + 1, bf_hi(v));
}

__global__ __launch_bounds__(256) void finalize(const float* __restrict__ x,
                                                const float* __restrict__ b,
                                                float* __restrict__ out,
                                                int n_vec4) {
    const int i = blockIdx.x * 256 + threadIdx.x;
    if (i >= n_vec4) return;
    float4 xv = ((const float4*)x)[i];
    float4 av = ((float4*)out)[i];
    const int dcol = (i * 4) & (NDIM - 1);
    float4 bv = *(const float4*)(b + dcol);
    float4 r;
    r.x = xv.x + fmaxf(av.x + bv.x, 0.f);
    r.y = xv.y + fmaxf(av.y + bv.y, 0.f);
    r.z = xv.z + fmaxf(av.z + bv.z, 0.f);
    r.w = xv.w + fmaxf(av.w + bv.w, 0.f);
    ((float4*)out)[i] = r;
}

extern "C" void kernel_launch(void* const* d_in, const int* in_sizes, int n_in,
                              void* d_out, int out_size, void* d_ws, size_t ws_size,
                              hipStream_t stream) {
    const float* x    = (const float*)d_in[0];
    const int*   esrc = (const int*)d_in[1];
    const int*   edst = (const int*)d_in[2];
    const float* W    = (const float*)d_in[3];
    const float* b    = (const float*)d_in[4];
    float* out = (float*)d_out;

    const int n_nodes = in_sizes[0] / NDIM;
    const int n_edges = in_sizes[1];
    const int nb = (n_nodes + BIN_NODES - 1) / BIN_NODES;
    const int ntiles = (n_nodes + 63) / 64;

    // Workspace layout
    unsigned short* h = (unsigned short*)d_ws;                 // N*128 bf16
    int* binCursor = (int*)(h + (size_t)n_nodes * NDIM);       // MAX_BINS
    unsigned int* binned = (unsigned int*)(binCursor + MAX_BINS);  // nb*BIN_CAP

    const size_t required = (size_t)n_nodes * NDIM * 2 +
                            (size_t)MAX_BINS * 4 +
                            ((size_t)nb << CAP_SHIFT) * 4;

    if (nb <= MAX_BINS && ws_size >= required) {
        hipMemsetAsync(binCursor, 0, (size_t)nb * sizeof(int), stream);

        const int gemmBlocks = (ntiles < 1024) ? ntiles : 1024;
        const int ntile_e = (n_edges + TILE - 1) / TILE;
        fused_gemm_bin<<<gemmBlocks + ntile_e, 256, 0, stream>>>(
            x, W, h, esrc, edst, binCursor, binned,
            n_nodes, ntiles, n_edges, nb, gemmBlocks);

        gather_bin<<<4 * nb, 256, 0, stream>>>(h, binned, binCursor, x, b, out, n_nodes);
    } else {
        // fallback: standalone gemm + atomic scatter
        const int gblocks = (ntiles < 2048) ? ntiles : 2048;
        gemm128_bf16<<<gblocks, 256, 0, stream>>>(x, W, h, n_nodes, ntiles);
        hipMemsetAsync(d_out, 0, (size_t)out_size * sizeof(float), stream);
        const long long st = (long long)n_edges * 64;
        scatter_add_bf<<<(int)((st + 255) / 256), 256, 0, stream>>>(h, esrc, edst, out, n_edges);
        const int n_vec4 = n_nodes * NDIM / 4;
        finalize<<<(n_vec4 + 255) / 256, 256, 0, stream>>>(x, b, out, n_vec4);
    }
}

// Round 17
// 127.521 us; speedup vs baseline: 1.0331x; 1.0331x over previous
//
#include <hip/hip_runtime.h>

#define NDIM 128
#define BIN_SHIFT 7
#define BIN_NODES 128          // 1 << BIN_SHIFT
#define MAX_BINS 1024          // supports up to 131072 nodes
#define TILE 4096              // edges per bin-role block
#define CAP_SHIFT 12
#define BIN_CAP 4096           // padded per-bin capacity (avg fill ~2046)
#define HALF_CAP 4096          // per-half-bin LDS sorted-src capacity

typedef __attribute__((ext_vector_type(8))) short short8;
typedef __attribute__((ext_vector_type(4))) float f32x4;
typedef __attribute__((ext_vector_type(4))) unsigned int u32x4;

__device__ inline unsigned short f2bf_rne(float f) {
    unsigned int u = __float_as_uint(f);
    unsigned int r = u + 0x7fffu + ((u >> 16) & 1u);
    return (unsigned short)(r >> 16);
}
__device__ inline float bf2f(unsigned short s) {
    return __uint_as_float(((unsigned int)s) << 16);
}
__device__ inline float bf_lo(unsigned int u) { return __uint_as_float(u << 16); }
__device__ inline float bf_hi(unsigned int u) { return __uint_as_float(u & 0xffff0000u); }

// HW packed f32->bf16 (RNE): dst = {lo16=bf16(a), hi16=bf16(b)}
__device__ inline unsigned int cvt_pk_bf16(float a, float b) {
    unsigned int r;
    asm("v_cvt_pk_bf16_f32 %0, %1, %2" : "=v"(r) : "v"(a), "v"(b));
    return r;
}

// ---------------------------------------------------------------------------
// fused_gemm_bin: STRIPED block-role split so both roles co-reside per CU.
//   (blockIdx & 3) == 3 : bin-scatter tile (idx = blockIdx>>2, ntile_e total)
//   else                : gemm grid-stride (idx = (blockIdx>>2)*3 + (blockIdx&3),
//                         gemmBlocks = 3*ntile_e)
// Gemm role keeps B-fragments t=0..3 in registers; t=4..7 read from LDS.
// binCursor is RELATIVE (memset 0 before launch).
// ---------------------------------------------------------------------------
__global__ __launch_bounds__(256, 4) void fused_gemm_bin(const float* __restrict__ x,
                                                         const float* __restrict__ W,
                                                         unsigned short* __restrict__ h,
                                                         const int* __restrict__ src,
                                                         const int* __restrict__ dst,
                                                         int* __restrict__ binCursor,
                                                         unsigned int* __restrict__ binned,
                                                         int n_nodes, int ntiles,
                                                         int n_edges, int nb,
                                                         int gemmBlocks) {
    __shared__ __align__(16) char smem[38144];
    const int tid = threadIdx.x;
    const int rrole = (int)blockIdx.x & 3;
    const int quad = (int)blockIdx.x >> 2;

    if (rrole != 3) {
        // ------------------- GEMM role -------------------
        unsigned short* Wt = (unsigned short*)smem;  // [128][128] bf16, k-swizzled

        const float4* W4 = (const float4*)W;
#pragma unroll
        for (int i = 0; i < 16; ++i) {
            const int vid = i * 256 + tid;
            const int k = vid >> 5;
            const int c4 = (vid & 31) * 4;
            const float4 w = W4[vid];
            const float* wf = (const float*)&w;
#pragma unroll
            for (int j = 0; j < 4; ++j) {
                const int col = c4 + j;
                const int ksw = k ^ ((col & 7) << 3);
                Wt[col * NDIM + ksw] = f2bf_rne(wf[j]);
            }
        }
        __syncthreads();

        const int wave = tid >> 6;
        const int lane = tid & 63;
        const int lc = lane & 15;
        const int kq = (lane >> 4) * 8;

        // B-fragments for t=0..3 in registers (tile-invariant)
        short8 breg[4][4];  // [ks][t]
#pragma unroll
        for (int ks = 0; ks < 4; ++ks) {
#pragma unroll
            for (int t = 0; t < 4; ++t) {
                const int col = t * 16 + lc;
                const int ksw = (ks * 32 + kq) ^ ((col & 7) << 3);
                breg[ks][t] = *(const short8*)&Wt[col * NDIM + ksw];
            }
        }

        const int gidx = quad * 3 + rrole;
        for (int tile = gidx; tile < ntiles; tile += gemmBlocks) {
            const int row0 = tile * 64 + wave * 16;

            int arow = row0 + lc;
            arow = (arow < n_nodes) ? arow : (n_nodes - 1);
            const float* xr = x + (size_t)arow * NDIM;

            f32x4 acc[8];
#pragma unroll
            for (int t = 0; t < 8; ++t) acc[t] = (f32x4){0.f, 0.f, 0.f, 0.f};

#pragma unroll
            for (int ks = 0; ks < 4; ++ks) {
                const int kbase = ks * 32 + kq;
                const float4 v0 = *(const float4*)(xr + kbase);
                const float4 v1 = *(const float4*)(xr + kbase + 4);

                u32x4 ap;
                ap.x = cvt_pk_bf16(v0.x, v0.y);
                ap.y = cvt_pk_bf16(v0.z, v0.w);
                ap.z = cvt_pk_bf16(v1.x, v1.y);
                ap.w = cvt_pk_bf16(v1.z, v1.w);
                const short8 ah = *(const short8*)&ap;

#pragma unroll
                for (int t = 0; t < 4; ++t) {
                    acc[t] = __builtin_amdgcn_mfma_f32_16x16x32_bf16(ah, breg[ks][t], acc[t], 0, 0, 0);
                }
#pragma unroll
                for (int t = 4; t < 8; ++t) {
                    const int col = t * 16 + lc;
                    const int ksw = kbase ^ ((col & 7) << 3);
                    const short8 bh = *(const short8*)&Wt[col * NDIM + ksw];
                    acc[t] = __builtin_amdgcn_mfma_f32_16x16x32_bf16(ah, bh, acc[t], 0, 0, 0);
                }
            }

            const int orow0 = row0 + (lane >> 4) * 4;
#pragma unroll
            for (int t = 0; t < 8; ++t) {
#pragma unroll
                for (int r = 0; r < 4; ++r) {
                    const int row = orow0 + r;
                    if (row < n_nodes) {
                        h[(size_t)row * NDIM + t * 16 + lc] = f2bf_rne(acc[t][r]);
                    }
                }
            }
        }
        return;
    }

    // ------------------- BIN role -------------------
    int* lhist  = (int*)smem;                                  //  4096 B
    int* lstart = lhist + MAX_BINS;                            //  4096 B
    int* lcur   = lstart + MAX_BINS;                           //  4096 B
    int* lsums  = lcur + MAX_BINS;                             //  1024 B
    unsigned int* lsorted = (unsigned int*)(lsums + 256);      // 16384 B
    unsigned short* lbin  = (unsigned short*)(lsorted + TILE); //  8192 B (sum 37888)

    const int base = quad * TILE;
    if (base >= n_edges) return;
    const int count = min(TILE, n_edges - base);

    for (int i = tid; i < MAX_BINS; i += 256) lhist[i] = 0;
    __syncthreads();

    int mybin[16];
    unsigned int mypacked[16];
#pragma unroll
    for (int j = 0; j < 16; ++j) {
        const int idx = tid + j * 256;  // coalesced
        if (idx < count) {
            const int d = __builtin_nontemporal_load(dst + base + idx);
            const int s = __builtin_nontemporal_load(src + base + idx);
            mybin[j] = d >> BIN_SHIFT;
            mypacked[j] = ((unsigned int)(d & (BIN_NODES - 1)) << 24) | (unsigned int)s;
            atomicAdd(&lhist[mybin[j]], 1);
        } else {
            mybin[j] = -1;
            mypacked[j] = 0;
        }
    }
    __syncthreads();

    // exclusive scan over MAX_BINS=1024 (4 elems/thread)
    const int a0 = lhist[4 * tid], a1 = lhist[4 * tid + 1];
    const int a2 = lhist[4 * tid + 2], a3 = lhist[4 * tid + 3];
    lsums[tid] = a0 + a1 + a2 + a3;
    __syncthreads();
    for (int off = 1; off < 256; off <<= 1) {
        const int tmp = (tid >= off) ? lsums[tid - off] : 0;
        __syncthreads();
        lsums[tid] += tmp;
        __syncthreads();
    }
    int ex = (tid > 0) ? lsums[tid - 1] : 0;
    lstart[4 * tid] = ex;
    lcur[4 * tid] = ex;
    ex += a0;
    lstart[4 * tid + 1] = ex;
    lcur[4 * tid + 1] = ex;
    ex += a1;
    lstart[4 * tid + 2] = ex;
    lcur[4 * tid + 2] = ex;
    ex += a2;
    lstart[4 * tid + 3] = ex;
    lcur[4 * tid + 3] = ex;
    __syncthreads();

    // LDS scatter into bin-sorted order + bin LUT
#pragma unroll
    for (int j = 0; j < 16; ++j) {
        if (mybin[j] >= 0) {
            const int pos = atomicAdd(&lcur[mybin[j]], 1);
            lsorted[pos] = mypacked[j];
            lbin[pos] = (unsigned short)mybin[j];
        }
    }
    __syncthreads();

    // reserve global runs per bin (lcur becomes RELATIVE base per bin)
    for (int i = tid; i < nb; i += 256) {
        const int c = lhist[i];
        lcur[i] = c ? atomicAdd(&binCursor[i], c) : 0;
    }
    __syncthreads();

    // sequential write-out; per-slot bin via LUT
    for (int p = tid; p < count; p += 256) {
        const int bn = lbin[p];
        const int rel = lcur[bn] + (p - lstart[bn]);
        if (rel < BIN_CAP) {  // overflow guard
            binned[((size_t)bn << CAP_SHIFT) + rel] = lsorted[p];
        }
    }
}

// ---------------------------------------------------------------------------
// gather_bin: TWO blocks (512 thr each) per 128-node bin; each block owns a
// 64-node half. In-LDS CSR build (filtered hist -> scan -> scatter into
// lout), then each of 8 waves gathers 8 nodes: 8-deep h-row unroll, fused
// epilogue out[n] = x[n] + relu(sum h[src] + b).
// ---------------------------------------------------------------------------
__global__ __launch_bounds__(512) void gather_bin(const unsigned short* __restrict__ h,
                                                  const unsigned int* __restrict__ binned,
                                                  const int* __restrict__ binCursor,
                                                  const float* __restrict__ x,
                                                  const float* __restrict__ bias,
                                                  float* __restrict__ out,
                                                  int n_nodes) {
    __shared__ int lhist[64];
    __shared__ int lstart[64];
    __shared__ int lcur[64];
    __shared__ int lout[HALF_CAP];
    const int b = blockIdx.x >> 1;
    const int half = (int)blockIdx.x & 1;
    const int tid = threadIdx.x;
    const size_t gbase = (size_t)b << CAP_SHIFT;
    int count = min(binCursor[b], BIN_CAP);
    const int node0 = b * BIN_NODES + half * 64;
    if (node0 >= n_nodes) return;

    if (tid < 64) lhist[tid] = 0;
    __syncthreads();

    // pass 1: filtered histogram (this block's 64-node half)
    for (int p = tid; p < count; p += 512) {
        const int dl = (int)(binned[gbase + p] >> 24);
        if ((dl >> 6) == half) atomicAdd(&lhist[dl & 63], 1);
    }
    __syncthreads();

    // inclusive scan of lhist[64] (Hillis-Steele, 64 lanes active)
    if (tid < 64) lstart[tid] = lhist[tid];
    __syncthreads();
    for (int off = 1; off < 64; off <<= 1) {
        int v = 0;
        if (tid < 64 && tid >= off) v = lstart[tid - off];
        __syncthreads();
        if (tid < 64 && tid >= off) lstart[tid] += v;
        __syncthreads();
    }
    int ex = 0;
    if (tid < 64) ex = (tid > 0) ? lstart[tid - 1] : 0;
    __syncthreads();
    if (tid < 64) {
        lstart[tid] = ex;
        lcur[tid] = ex;
    }
    __syncthreads();

    // pass 2: filtered scatter of src into per-node groups (binned L2-hot)
    for (int p = tid; p < count; p += 512) {
        const unsigned int v = binned[gbase + p];
        const int dl = (int)(v >> 24);
        if ((dl >> 6) == half) {
            const int pos = atomicAdd(&lcur[dl & 63], 1);
            if (pos < HALF_CAP) lout[pos] = (int)(v & 0xFFFFFFu);
        }
    }
    __syncthreads();

    // gather: wave w handles local nodes w*8 .. w*8+7 serially
    const int wave = tid >> 6;
    const int lane = tid & 63;
    const int c = lane * 2;
    const float2 bv = *(const float2*)(bias + c);

#pragma unroll 1
    for (int i = 0; i < 8; ++i) {
        const int ln = wave * 8 + i;
        const int node = node0 + ln;
        if (node >= n_nodes) break;
        const int start = lstart[ln];
        int cnt = lhist[ln];
        if (start + cnt > HALF_CAP) cnt = HALF_CAP - start;  // never in practice

        float ax = 0.f, ay = 0.f;
        int j = 0;
        for (; j + 8 <= cnt; j += 8) {
            int s[8];
#pragma unroll
            for (int k = 0; k < 8; ++k) s[k] = lout[start + j + k];
            unsigned int v[8];
#pragma unroll
            for (int k = 0; k < 8; ++k) v[k] = *(const unsigned int*)(h + (size_t)s[k] * NDIM + c);
#pragma unroll
            for (int k = 0; k < 8; ++k) { ax += bf_lo(v[k]); ay += bf_hi(v[k]); }
        }
        for (; j + 4 <= cnt; j += 4) {
            int s[4];
#pragma unroll
            for (int k = 0; k < 4; ++k) s[k] = lout[start + j + k];
            unsigned int v[4];
#pragma unroll
            for (int k = 0; k < 4; ++k) v[k] = *(const unsigned int*)(h + (size_t)s[k] * NDIM + c);
#pragma unroll
            for (int k = 0; k < 4; ++k) { ax += bf_lo(v[k]); ay += bf_hi(v[k]); }
        }
        for (; j < cnt; ++j) {
            const int s0 = lout[start + j];
            const unsigned int v0 = *(const unsigned int*)(h + (size_t)s0 * NDIM + c);
            ax += bf_lo(v0);
            ay += bf_hi(v0);
        }

        const float2 xv = *(const float2*)(x + (size_t)node * NDIM + c);
        float2 r;
        r.x = xv.x + fmaxf(ax + bv.x, 0.f);
        r.y = xv.y + fmaxf(ay + bv.y, 0.f);
        *(float2*)(out + (size_t)node * NDIM + c) = r;
    }
}

// ---------------------------------------------------------------------------
// Fallback GEMM (standalone) + atomic scatter, used only if ws too small.
// ---------------------------------------------------------------------------
__global__ __launch_bounds__(256) void gemm128_bf16(const float* __restrict__ x,
                                                    const float* __restrict__ W,
                                                    unsigned short* __restrict__ h,
                                                    int n_nodes, int ntiles) {
    __shared__ __align__(16) unsigned short Wt[NDIM * NDIM];
    const int tid = threadIdx.x;
    const float4* W4 = (const float4*)W;
#pragma unroll
    for (int i = 0; i < 16; ++i) {
        const int vid = i * 256 + tid;
        const int k = vid >> 5;
        const int c4 = (vid & 31) * 4;
        const float4 w = W4[vid];
        const float* wf = (const float*)&w;
#pragma unroll
        for (int j = 0; j < 4; ++j) {
            const int col = c4 + j;
            const int ksw = k ^ ((col & 7) << 3);
            Wt[col * NDIM + ksw] = f2bf_rne(wf[j]);
        }
    }
    __syncthreads();
    const int wave = tid >> 6;
    const int lane = tid & 63;
    const int lc = lane & 15;
    const int kq = (lane >> 4) * 8;
    for (int tile = blockIdx.x; tile < ntiles; tile += gridDim.x) {
        const int row0 = tile * 64 + wave * 16;
        int arow = row0 + lc;
        arow = (arow < n_nodes) ? arow : (n_nodes - 1);
        const float* xr = x + (size_t)arow * NDIM;
        f32x4 acc[8];
#pragma unroll
        for (int t = 0; t < 8; ++t) acc[t] = (f32x4){0.f, 0.f, 0.f, 0.f};
#pragma unroll
        for (int ks = 0; ks < 4; ++ks) {
            const int kbase = ks * 32 + kq;
            const float4 v0 = *(const float4*)(xr + kbase);
            const float4 v1 = *(const float4*)(xr + kbase + 4);
            u32x4 ap;
            ap.x = cvt_pk_bf16(v0.x, v0.y);
            ap.y = cvt_pk_bf16(v0.z, v0.w);
            ap.z = cvt_pk_bf16(v1.x, v1.y);
            ap.w = cvt_pk_bf16(v1.z, v1.w);
            const short8 ah = *(const short8*)&ap;
#pragma unroll
            for (int t = 0; t < 8; ++t) {
                const int col = t * 16 + lc;
                const int ksw = kbase ^ ((col & 7) << 3);
                const short8 bh = *(const short8*)&Wt[col * NDIM + ksw];
                acc[t] = __builtin_amdgcn_mfma_f32_16x16x32_bf16(ah, bh, acc[t], 0, 0, 0);
            }
        }
        const int orow0 = row0 + (lane >> 4) * 4;
#pragma unroll
        for (int t = 0; t < 8; ++t) {
#pragma unroll
            for (int r = 0; r < 4; ++r) {
                const int row = orow0 + r;
                if (row < n_nodes) {
                    h[(size_t)row * NDIM + t * 16 + lc] = f2bf_rne(acc[t][r]);
                }
            }
        }
    }
}

__global__ __launch_bounds__(256) void scatter_add_bf(const unsigned short* __restrict__ h,
                                                      const int* __restrict__ src,
                                                      const int* __restrict__ dst,
                                                      float* __restrict__ agg,
                                                      int n_edges) {
    const int gid = blockIdx.x * 256 + threadIdx.x;
    const int e = gid >> 6;
    if (e >= n_edges) return;
    const int c = (gid & 63) * 2;
    const int s = src[e];
    const int d = dst[e];
    const unsigned int v = *(const unsigned int*)(h + (size_t)s * NDIM + c);
    float* ap = agg + (size_t)d * NDIM + c;
    atomicAdd(ap + 0, bf_lo(v));
    atomicAdd(ap + 1, bf_hi(v));
}

__global__ __launch_bounds__(256) void finalize(const float* __restrict__ x,
                                                const float* __restrict__ b,
                                                float* __restrict__ out,
                                                int n_vec4) {
    const int i = blockIdx.x * 256 + threadIdx.x;
    if (i >= n_vec4) return;
    float4 xv = ((const float4*)x)[i];
    float4 av = ((float4*)out)[i];
    const int dcol = (i * 4) & (NDIM - 1);
    float4 bv = *(const float4*)(b + dcol);
    float4 r;
    r.x = xv.x + fmaxf(av.x + bv.x, 0.f);
    r.y = xv.y + fmaxf(av.y + bv.y, 0.f);
    r.z = xv.z + fmaxf(av.z + bv.z, 0.f);
    r.w = xv.w + fmaxf(av.w + bv.w, 0.f);
    ((float4*)out)[i] = r;
}

extern "C" void kernel_launch(void* const* d_in, const int* in_sizes, int n_in,
                              void* d_out, int out_size, void* d_ws, size_t ws_size,
                              hipStream_t stream) {
    const float* x    = (const float*)d_in[0];
    const int*   esrc = (const int*)d_in[1];
    const int*   edst = (const int*)d_in[2];
    const float* W    = (const float*)d_in[3];
    const float* b    = (const float*)d_in[4];
    float* out = (float*)d_out;

    const int n_nodes = in_sizes[0] / NDIM;
    const int n_edges = in_sizes[1];
    const int nb = (n_nodes + BIN_NODES - 1) / BIN_NODES;
    const int ntiles = (n_nodes + 63) / 64;

    // Workspace layout
    unsigned short* h = (unsigned short*)d_ws;                 // N*128 bf16
    int* binCursor = (int*)(h + (size_t)n_nodes * NDIM);       // MAX_BINS
    unsigned int* binned = (unsigned int*)(binCursor + MAX_BINS);  // nb*BIN_CAP

    const size_t required = (size_t)n_nodes * NDIM * 2 +
                            (size_t)MAX_BINS * 4 +
                            ((size_t)nb << CAP_SHIFT) * 4;

    if (nb <= MAX_BINS && ws_size >= required) {
        hipMemsetAsync(binCursor, 0, (size_t)nb * sizeof(int), stream);

        const int ntile_e = (n_edges + TILE - 1) / TILE;
        const int gemmBlocks = 3 * ntile_e;   // striped 3:1 with bin blocks
        fused_gemm_bin<<<4 * ntile_e, 256, 0, stream>>>(
            x, W, h, esrc, edst, binCursor, binned,
            n_nodes, ntiles, n_edges, nb, gemmBlocks);

        gather_bin<<<2 * nb, 512, 0, stream>>>(h, binned, binCursor, x, b, out, n_nodes);
    } else {
        // fallback: standalone gemm + atomic scatter
        const int gblocks = (ntiles < 2048) ? ntiles : 2048;
        gemm128_bf16<<<gblocks, 256, 0, stream>>>(x, W, h, n_nodes, ntiles);
        hipMemsetAsync(d_out, 0, (size_t)out_size * sizeof(float), stream);
        const long long st = (long long)n_edges * 64;
        scatter_add_bf<<<(int)((st + 255) / 256), 256, 0, stream>>>(h, esrc, edst, out, n_edges);
        const int n_vec4 = n_nodes * NDIM / 4;
        finalize<<<(n_vec4 + 255) / 256, 256, 0, stream>>>(x, b, out, n_vec4);
    }
}

// Round 18
// 117.553 us; speedup vs baseline: 1.1207x; 1.0848x over previous
//
#include <hip/hip_runtime.h>

#define NDIM 128
#define BIN_SHIFT 7
#define BIN_NODES 128          // 1 << BIN_SHIFT
#define MAX_BINS 1024          // supports up to 131072 nodes
#define TILE 4096              // edges per bin-role block
#define CAP_SHIFT 12
#define BIN_CAP 4096           // padded per-bin capacity (avg fill ~2046)
#define HALF_CAP 4096          // per-half-bin LDS sorted-src capacity

typedef __attribute__((ext_vector_type(8))) short short8;
typedef __attribute__((ext_vector_type(4))) float f32x4;
typedef __attribute__((ext_vector_type(4))) unsigned int u32x4;

__device__ inline unsigned short f2bf_rne(float f) {
    unsigned int u = __float_as_uint(f);
    unsigned int r = u + 0x7fffu + ((u >> 16) & 1u);
    return (unsigned short)(r >> 16);
}
__device__ inline float bf2f(unsigned short s) {
    return __uint_as_float(((unsigned int)s) << 16);
}
__device__ inline float bf_lo(unsigned int u) { return __uint_as_float(u << 16); }
__device__ inline float bf_hi(unsigned int u) { return __uint_as_float(u & 0xffff0000u); }

// HW packed f32->bf16 (RNE): dst = {lo16=bf16(a), hi16=bf16(b)}
__device__ inline unsigned int cvt_pk_bf16(float a, float b) {
    unsigned int r;
    asm("v_cvt_pk_bf16_f32 %0, %1, %2" : "=v"(r) : "v"(a), "v"(b));
    return r;
}

// ---------------------------------------------------------------------------
// fused_gemm_bin: block-role split (data-independent roles co-resident).
//   blocks [0, gemmBlocks)          : h = x @ W (pure bf16 MFMA, grid-stride,
//                                     ~3 tiles/block to amortize W staging)
//   blocks [gemmBlocks, +ntile_e)   : bin-scatter tile of TILE edges into
//                                     128-node bins (packed dstLow<<24|src).
// Gemm role keeps B-fragments t=0..3 in registers; t=4..7 read from LDS.
// binCursor is RELATIVE (memset 0 before launch).
// ---------------------------------------------------------------------------
__global__ __launch_bounds__(256, 4) void fused_gemm_bin(const float* __restrict__ x,
                                                         const float* __restrict__ W,
                                                         unsigned short* __restrict__ h,
                                                         const int* __restrict__ src,
                                                         const int* __restrict__ dst,
                                                         int* __restrict__ binCursor,
                                                         unsigned int* __restrict__ binned,
                                                         int n_nodes, int ntiles,
                                                         int n_edges, int nb,
                                                         int gemmBlocks) {
    __shared__ __align__(16) char smem[38144];
    const int tid = threadIdx.x;

    if ((int)blockIdx.x < gemmBlocks) {
        // ------------------- GEMM role -------------------
        unsigned short* Wt = (unsigned short*)smem;  // [128][128] bf16, k-swizzled

        const float4* W4 = (const float4*)W;
#pragma unroll
        for (int i = 0; i < 16; ++i) {
            const int vid = i * 256 + tid;
            const int k = vid >> 5;
            const int c4 = (vid & 31) * 4;
            const float4 w = W4[vid];
            const float* wf = (const float*)&w;
#pragma unroll
            for (int j = 0; j < 4; ++j) {
                const int col = c4 + j;
                const int ksw = k ^ ((col & 7) << 3);
                Wt[col * NDIM + ksw] = f2bf_rne(wf[j]);
            }
        }
        __syncthreads();

        const int wave = tid >> 6;
        const int lane = tid & 63;
        const int lc = lane & 15;
        const int kq = (lane >> 4) * 8;

        // B-fragments for t=0..3 in registers (tile-invariant)
        short8 breg[4][4];  // [ks][t]
#pragma unroll
        for (int ks = 0; ks < 4; ++ks) {
#pragma unroll
            for (int t = 0; t < 4; ++t) {
                const int col = t * 16 + lc;
                const int ksw = (ks * 32 + kq) ^ ((col & 7) << 3);
                breg[ks][t] = *(const short8*)&Wt[col * NDIM + ksw];
            }
        }

        for (int tile = blockIdx.x; tile < ntiles; tile += gemmBlocks) {
            const int row0 = tile * 64 + wave * 16;

            int arow = row0 + lc;
            arow = (arow < n_nodes) ? arow : (n_nodes - 1);
            const float* xr = x + (size_t)arow * NDIM;

            f32x4 acc[8];
#pragma unroll
            for (int t = 0; t < 8; ++t) acc[t] = (f32x4){0.f, 0.f, 0.f, 0.f};

#pragma unroll
            for (int ks = 0; ks < 4; ++ks) {
                const int kbase = ks * 32 + kq;
                const float4 v0 = *(const float4*)(xr + kbase);
                const float4 v1 = *(const float4*)(xr + kbase + 4);

                u32x4 ap;
                ap.x = cvt_pk_bf16(v0.x, v0.y);
                ap.y = cvt_pk_bf16(v0.z, v0.w);
                ap.z = cvt_pk_bf16(v1.x, v1.y);
                ap.w = cvt_pk_bf16(v1.z, v1.w);
                const short8 ah = *(const short8*)&ap;

#pragma unroll
                for (int t = 0; t < 4; ++t) {
                    acc[t] = __builtin_amdgcn_mfma_f32_16x16x32_bf16(ah, breg[ks][t], acc[t], 0, 0, 0);
                }
#pragma unroll
                for (int t = 4; t < 8; ++t) {
                    const int col = t * 16 + lc;
                    const int ksw = kbase ^ ((col & 7) << 3);
                    const short8 bh = *(const short8*)&Wt[col * NDIM + ksw];
                    acc[t] = __builtin_amdgcn_mfma_f32_16x16x32_bf16(ah, bh, acc[t], 0, 0, 0);
                }
            }

            const int orow0 = row0 + (lane >> 4) * 4;
#pragma unroll
            for (int t = 0; t < 8; ++t) {
#pragma unroll
                for (int r = 0; r < 4; ++r) {
                    const int row = orow0 + r;
                    if (row < n_nodes) {
                        h[(size_t)row * NDIM + t * 16 + lc] = f2bf_rne(acc[t][r]);
                    }
                }
            }
        }
        return;
    }

    // ------------------- BIN role -------------------
    int* lhist  = (int*)smem;                                  //  4096 B
    int* lstart = lhist + MAX_BINS;                            //  4096 B
    int* lcur   = lstart + MAX_BINS;                           //  4096 B
    int* lsums  = lcur + MAX_BINS;                             //  1024 B
    unsigned int* lsorted = (unsigned int*)(lsums + 256);      // 16384 B
    unsigned short* lbin  = (unsigned short*)(lsorted + TILE); //  8192 B (sum 37888)

    const int bblk = (int)blockIdx.x - gemmBlocks;
    const int base = bblk * TILE;
    if (base >= n_edges) return;
    const int count = min(TILE, n_edges - base);

    for (int i = tid; i < MAX_BINS; i += 256) lhist[i] = 0;
    __syncthreads();

    int mybin[16];
    unsigned int mypacked[16];
#pragma unroll
    for (int j = 0; j < 16; ++j) {
        const int idx = tid + j * 256;  // coalesced
        if (idx < count) {
            const int d = __builtin_nontemporal_load(dst + base + idx);
            const int s = __builtin_nontemporal_load(src + base + idx);
            mybin[j] = d >> BIN_SHIFT;
            mypacked[j] = ((unsigned int)(d & (BIN_NODES - 1)) << 24) | (unsigned int)s;
            atomicAdd(&lhist[mybin[j]], 1);
        } else {
            mybin[j] = -1;
            mypacked[j] = 0;
        }
    }
    __syncthreads();

    // exclusive scan over MAX_BINS=1024 (4 elems/thread)
    const int a0 = lhist[4 * tid], a1 = lhist[4 * tid + 1];
    const int a2 = lhist[4 * tid + 2], a3 = lhist[4 * tid + 3];
    lsums[tid] = a0 + a1 + a2 + a3;
    __syncthreads();
    for (int off = 1; off < 256; off <<= 1) {
        const int tmp = (tid >= off) ? lsums[tid - off] : 0;
        __syncthreads();
        lsums[tid] += tmp;
        __syncthreads();
    }
    int ex = (tid > 0) ? lsums[tid - 1] : 0;
    lstart[4 * tid] = ex;
    lcur[4 * tid] = ex;
    ex += a0;
    lstart[4 * tid + 1] = ex;
    lcur[4 * tid + 1] = ex;
    ex += a1;
    lstart[4 * tid + 2] = ex;
    lcur[4 * tid + 2] = ex;
    ex += a2;
    lstart[4 * tid + 3] = ex;
    lcur[4 * tid + 3] = ex;
    __syncthreads();

    // LDS scatter into bin-sorted order + bin LUT
#pragma unroll
    for (int j = 0; j < 16; ++j) {
        if (mybin[j] >= 0) {
            const int pos = atomicAdd(&lcur[mybin[j]], 1);
            lsorted[pos] = mypacked[j];
            lbin[pos] = (unsigned short)mybin[j];
        }
    }
    __syncthreads();

    // reserve global runs per bin (lcur becomes RELATIVE base per bin)
    for (int i = tid; i < nb; i += 256) {
        const int c = lhist[i];
        lcur[i] = c ? atomicAdd(&binCursor[i], c) : 0;
    }
    __syncthreads();

    // sequential write-out; per-slot bin via LUT
    for (int p = tid; p < count; p += 256) {
        const int bn = lbin[p];
        const int rel = lcur[bn] + (p - lstart[bn]);
        if (rel < BIN_CAP) {  // overflow guard
            binned[((size_t)bn << CAP_SHIFT) + rel] = lsorted[p];
        }
    }
}

// ---------------------------------------------------------------------------
// gather_bin: TWO blocks (512 thr each) per 128-node bin; each block owns a
// 64-node half. In-LDS CSR build (filtered hist -> scan -> scatter into
// lout), then each of 8 waves gathers 8 nodes: 8-deep h-row unroll, fused
// epilogue out[n] = x[n] + relu(sum h[src] + b).
// ---------------------------------------------------------------------------
__global__ __launch_bounds__(512) void gather_bin(const unsigned short* __restrict__ h,
                                                  const unsigned int* __restrict__ binned,
                                                  const int* __restrict__ binCursor,
                                                  const float* __restrict__ x,
                                                  const float* __restrict__ bias,
                                                  float* __restrict__ out,
                                                  int n_nodes) {
    __shared__ int lhist[64];
    __shared__ int lstart[64];
    __shared__ int lcur[64];
    __shared__ int lout[HALF_CAP];
    const int b = blockIdx.x >> 1;
    const int half = (int)blockIdx.x & 1;
    const int tid = threadIdx.x;
    const size_t gbase = (size_t)b << CAP_SHIFT;
    int count = min(binCursor[b], BIN_CAP);
    const int node0 = b * BIN_NODES + half * 64;
    if (node0 >= n_nodes) return;

    if (tid < 64) lhist[tid] = 0;
    __syncthreads();

    // pass 1: filtered histogram (this block's 64-node half)
    for (int p = tid; p < count; p += 512) {
        const int dl = (int)(binned[gbase + p] >> 24);
        if ((dl >> 6) == half) atomicAdd(&lhist[dl & 63], 1);
    }
    __syncthreads();

    // inclusive scan of lhist[64] (Hillis-Steele, 64 lanes active)
    if (tid < 64) lstart[tid] = lhist[tid];
    __syncthreads();
    for (int off = 1; off < 64; off <<= 1) {
        int v = 0;
        if (tid < 64 && tid >= off) v = lstart[tid - off];
        __syncthreads();
        if (tid < 64 && tid >= off) lstart[tid] += v;
        __syncthreads();
    }
    int ex = 0;
    if (tid < 64) ex = (tid > 0) ? lstart[tid - 1] : 0;
    __syncthreads();
    if (tid < 64) {
        lstart[tid] = ex;
        lcur[tid] = ex;
    }
    __syncthreads();

    // pass 2: filtered scatter of src into per-node groups (binned L2-hot)
    for (int p = tid; p < count; p += 512) {
        const unsigned int v = binned[gbase + p];
        const int dl = (int)(v >> 24);
        if ((dl >> 6) == half) {
            const int pos = atomicAdd(&lcur[dl & 63], 1);
            if (pos < HALF_CAP) lout[pos] = (int)(v & 0xFFFFFFu);
        }
    }
    __syncthreads();

    // gather: wave w handles local nodes w*8 .. w*8+7 serially
    const int wave = tid >> 6;
    const int lane = tid & 63;
    const int c = lane * 2;
    const float2 bv = *(const float2*)(bias + c);

#pragma unroll 1
    for (int i = 0; i < 8; ++i) {
        const int ln = wave * 8 + i;
        const int node = node0 + ln;
        if (node >= n_nodes) break;
        const int start = lstart[ln];
        int cnt = lhist[ln];
        if (start + cnt > HALF_CAP) cnt = HALF_CAP - start;  // never in practice

        float ax = 0.f, ay = 0.f;
        int j = 0;
        for (; j + 8 <= cnt; j += 8) {
            int s[8];
#pragma unroll
            for (int k = 0; k < 8; ++k) s[k] = lout[start + j + k];
            unsigned int v[8];
#pragma unroll
            for (int k = 0; k < 8; ++k) v[k] = *(const unsigned int*)(h + (size_t)s[k] * NDIM + c);
#pragma unroll
            for (int k = 0; k < 8; ++k) { ax += bf_lo(v[k]); ay += bf_hi(v[k]); }
        }
        for (; j + 4 <= cnt; j += 4) {
            int s[4];
#pragma unroll
            for (int k = 0; k < 4; ++k) s[k] = lout[start + j + k];
            unsigned int v[4];
#pragma unroll
            for (int k = 0; k < 4; ++k) v[k] = *(const unsigned int*)(h + (size_t)s[k] * NDIM + c);
#pragma unroll
            for (int k = 0; k < 4; ++k) { ax += bf_lo(v[k]); ay += bf_hi(v[k]); }
        }
        for (; j < cnt; ++j) {
            const int s0 = lout[start + j];
            const unsigned int v0 = *(const unsigned int*)(h + (size_t)s0 * NDIM + c);
            ax += bf_lo(v0);
            ay += bf_hi(v0);
        }

        const float2 xv = *(const float2*)(x + (size_t)node * NDIM + c);
        float2 r;
        r.x = xv.x + fmaxf(ax + bv.x, 0.f);
        r.y = xv.y + fmaxf(ay + bv.y, 0.f);
        *(float2*)(out + (size_t)node * NDIM + c) = r;
    }
}

// ---------------------------------------------------------------------------
// Fallback GEMM (standalone) + atomic scatter, used only if ws too small.
// ---------------------------------------------------------------------------
__global__ __launch_bounds__(256) void gemm128_bf16(const float* __restrict__ x,
                                                    const float* __restrict__ W,
                                                    unsigned short* __restrict__ h,
                                                    int n_nodes, int ntiles) {
    __shared__ __align__(16) unsigned short Wt[NDIM * NDIM];
    const int tid = threadIdx.x;
    const float4* W4 = (const float4*)W;
#pragma unroll
    for (int i = 0; i < 16; ++i) {
        const int vid = i * 256 + tid;
        const int k = vid >> 5;
        const int c4 = (vid & 31) * 4;
        const float4 w = W4[vid];
        const float* wf = (const float*)&w;
#pragma unroll
        for (int j = 0; j < 4; ++j) {
            const int col = c4 + j;
            const int ksw = k ^ ((col & 7) << 3);
            Wt[col * NDIM + ksw] = f2bf_rne(wf[j]);
        }
    }
    __syncthreads();
    const int wave = tid >> 6;
    const int lane = tid & 63;
    const int lc = lane & 15;
    const int kq = (lane >> 4) * 8;
    for (int tile = blockIdx.x; tile < ntiles; tile += gridDim.x) {
        const int row0 = tile * 64 + wave * 16;
        int arow = row0 + lc;
        arow = (arow < n_nodes) ? arow : (n_nodes - 1);
        const float* xr = x + (size_t)arow * NDIM;
        f32x4 acc[8];
#pragma unroll
        for (int t = 0; t < 8; ++t) acc[t] = (f32x4){0.f, 0.f, 0.f, 0.f};
#pragma unroll
        for (int ks = 0; ks < 4; ++ks) {
            const int kbase = ks * 32 + kq;
            const float4 v0 = *(const float4*)(xr + kbase);
            const float4 v1 = *(const float4*)(xr + kbase + 4);
            u32x4 ap;
            ap.x = cvt_pk_bf16(v0.x, v0.y);
            ap.y = cvt_pk_bf16(v0.z, v0.w);
            ap.z = cvt_pk_bf16(v1.x, v1.y);
            ap.w = cvt_pk_bf16(v1.z, v1.w);
            const short8 ah = *(const short8*)&ap;
#pragma unroll
            for (int t = 0; t < 8; ++t) {
                const int col = t * 16 + lc;
                const int ksw = kbase ^ ((col & 7) << 3);
                const short8 bh = *(const short8*)&Wt[col * NDIM + ksw];
                acc[t] = __builtin_amdgcn_mfma_f32_16x16x32_bf16(ah, bh, acc[t], 0, 0, 0);
            }
        }
        const int orow0 = row0 + (lane >> 4) * 4;
#pragma unroll
        for (int t = 0; t < 8; ++t) {
#pragma unroll
            for (int r = 0; r < 4; ++r) {
                const int row = orow0 + r;
                if (row < n_nodes) {
                    h[(size_t)row * NDIM + t * 16 + lc] = f2bf_rne(acc[t][r]);
                }
            }
        }
    }
}

__global__ __launch_bounds__(256) void scatter_add_bf(const unsigned short* __restrict__ h,
                                                      const int* __restrict__ src,
                                                      const int* __restrict__ dst,
                                                      float* __restrict__ agg,
                                                      int n_edges) {
    const int gid = blockIdx.x * 256 + threadIdx.x;
    const int e = gid >> 6;
    if (e >= n_edges) return;
    const int c = (gid & 63) * 2;
    const int s = src[e];
    const int d = dst[e];
    const unsigned int v = *(const unsigned int*)(h + (size_t)s * NDIM + c);
    float* ap = agg + (size_t)d * NDIM + c;
    atomicAdd(ap + 0, bf_lo(v));
    atomicAdd(ap + 1, bf_hi(v));
}

__global__ __launch_bounds__(256) void finalize(const float* __restrict__ x,
                                                const float* __restrict__ b,
                                                float* __restrict__ out,
                                                int n_vec4) {
    const int i = blockIdx.x * 256 + threadIdx.x;
    if (i >= n_vec4) return;
    float4 xv = ((const float4*)x)[i];
    float4 av = ((float4*)out)[i];
    const int dcol = (i * 4) & (NDIM - 1);
    float4 bv = *(const float4*)(b + dcol);
    float4 r;
    r.x = xv.x + fmaxf(av.x + bv.x, 0.f);
    r.y = xv.y + fmaxf(av.y + bv.y, 0.f);
    r.z = xv.z + fmaxf(av.z + bv.z, 0.f);
    r.w = xv.w + fmaxf(av.w + bv.w, 0.f);
    ((float4*)out)[i] = r;
}

extern "C" void kernel_launch(void* const* d_in, const int* in_sizes, int n_in,
                              void* d_out, int out_size, void* d_ws, size_t ws_size,
                              hipStream_t stream) {
    const float* x    = (const float*)d_in[0];
    const int*   esrc = (const int*)d_in[1];
    const int*   edst = (const int*)d_in[2];
    const float* W    = (const float*)d_in[3];
    const float* b    = (const float*)d_in[4];
    float* out = (float*)d_out;

    const int n_nodes = in_sizes[0] / NDIM;
    const int n_edges = in_sizes[1];
    const int nb = (n_nodes + BIN_NODES - 1) / BIN_NODES;
    const int ntiles = (n_nodes + 63) / 64;

    // Workspace layout
    unsigned short* h = (unsigned short*)d_ws;                 // N*128 bf16
    int* binCursor = (int*)(h + (size_t)n_nodes * NDIM);       // MAX_BINS
    unsigned int* binned = (unsigned int*)(binCursor + MAX_BINS);  // nb*BIN_CAP

    const size_t required = (size_t)n_nodes * NDIM * 2 +
                            (size_t)MAX_BINS * 4 +
                            ((size_t)nb << CAP_SHIFT) * 4;

    if (nb <= MAX_BINS && ws_size >= required) {
        hipMemsetAsync(binCursor, 0, (size_t)nb * sizeof(int), stream);

        const int ntile_e = (n_edges + TILE - 1) / TILE;
        const int gemmBlocks = (ntiles < 512) ? ntiles : 512;  // ~3 tiles/block
        fused_gemm_bin<<<gemmBlocks + ntile_e, 256, 0, stream>>>(
            x, W, h, esrc, edst, binCursor, binned,
            n_nodes, ntiles, n_edges, nb, gemmBlocks);

        gather_bin<<<2 * nb, 512, 0, stream>>>(h, binned, binCursor, x, b, out, n_nodes);
    } else {
        // fallback: standalone gemm + atomic scatter
        const int gblocks = (ntiles < 2048) ? ntiles : 2048;
        gemm128_bf16<<<gblocks, 256, 0, stream>>>(x, W, h, n_nodes, ntiles);
        hipMemsetAsync(d_out, 0, (size_t)out_size * sizeof(float), stream);
        const long long st = (long long)n_edges * 64;
        scatter_add_bf<<<(int)((st + 255) / 256), 256, 0, stream>>>(h, esrc, edst, out, n_edges);
        const int n_vec4 = n_nodes * NDIM / 4;
        finalize<<<(n_vec4 + 255) / 256, 256, 0, stream>>>(x, b, out, n_vec4);
    }
}